// Round 10
// baseline (502.385 us; speedup 1.0000x reference)
//
#include <hip/hip_runtime.h>
#include <math.h>

__host__ __device__ static inline int div_up(long long a, long long b) { return (int)((a + b - 1) / b); }

#define SCH 2048              // scan chunk per block
#define NXCD 8                // XCD slices for false-sharing-free placement
#define PM 256                // edge chunks for k_place_direct (grid = 8*PM)

typedef int int4v __attribute__((ext_vector_type(4)));

__device__ inline int4v nt_load4(const int* p) {
    return __builtin_nontemporal_load(reinterpret_cast<const int4v*>(p));
}
__device__ inline int nt_load1(const int* p) {
    return __builtin_nontemporal_load(p);
}

// ---------------- CSR build ----------------

__global__ void k_zero_i32(int* __restrict__ p, int n) {
    int i = blockIdx.x * blockDim.x + threadIdx.x;
    if (i < n) p[i] = 0;
}

__global__ void k_cnt(const int* __restrict__ dst, int* __restrict__ cnt, int E) {
    int i = (blockIdx.x * blockDim.x + threadIdx.x) * 4;
    if (i + 3 < E) {
        int4v d = nt_load4(dst + i);
        atomicAdd(&cnt[d.x], 1);
        atomicAdd(&cnt[d.y], 1);
        atomicAdd(&cnt[d.z], 1);
        atomicAdd(&cnt[d.w], 1);
    } else {
        for (int j = i; j < E; ++j) atomicAdd(&cnt[dst[j]], 1);
    }
}

// Phase 1: per-block sums of SCH-element chunks.
__global__ void k_scan_part(const int* __restrict__ cnt, int* __restrict__ bsum, int N) {
    __shared__ int ws[4];
    int base = blockIdx.x * SCH + threadIdx.x * 8;
    int t = 0;
#pragma unroll
    for (int j = 0; j < 8; ++j) {
        int idx = base + j;
        if (idx < N) t += cnt[idx];
    }
    for (int off = 32; off >= 1; off >>= 1) t += __shfl_xor(t, off);
    int lane = threadIdx.x & 63, wid = threadIdx.x >> 6;
    if (lane == 0) ws[wid] = t;
    __syncthreads();
    if (threadIdx.x == 0) bsum[blockIdx.x] = ws[0] + ws[1] + ws[2] + ws[3];
}

// Phase 2: exclusive scan of block sums (NB <= 1024) + grand total -> rpN.
__global__ void k_scan_bsums(int* __restrict__ bsum, int* __restrict__ rpN, int NB) {
    __shared__ int wsum[16];
    int tid = threadIdx.x;
    int v = (tid < NB) ? bsum[tid] : 0;
    int lane = tid & 63, wid = tid >> 6;
    int x = v;
    for (int off = 1; off < 64; off <<= 1) {
        int y = __shfl_up(x, off);
        if (lane >= off) x += y;
    }
    if (lane == 63) wsum[wid] = x;
    __syncthreads();
    if (tid < 16) {
        int s = wsum[tid];
        for (int off = 1; off < 16; off <<= 1) {
            int y = __shfl_up(s, off);
            if (tid >= off) s += y;
        }
        wsum[tid] = s;
    }
    __syncthreads();
    int woff = (wid > 0) ? wsum[wid - 1] : 0;
    int excl = woff + x - v;
    if (tid < NB) bsum[tid] = excl;
    if (tid == NB - 1) rpN[0] = excl + v;
}

// Phase 3: local exclusive scan + block offset; emits rp, cur, dis.
__global__ void k_scan_apply(const int* __restrict__ cnt, const int* __restrict__ bsum,
                             int* __restrict__ rp, int* __restrict__ cur,
                             float* __restrict__ dis, int N) {
    __shared__ int wsum[4];
    int tid = threadIdx.x;
    int base = blockIdx.x * SCH + tid * 8;
    int v[8];
    int t = 0;
#pragma unroll
    for (int j = 0; j < 8; ++j) {
        int idx = base + j;
        v[j] = (idx < N) ? cnt[idx] : 0;
        t += v[j];
    }
    int lane = tid & 63, wid = tid >> 6;
    int x = t;
    for (int off = 1; off < 64; off <<= 1) {
        int y = __shfl_up(x, off);
        if (lane >= off) x += y;
    }
    if (lane == 63) wsum[wid] = x;
    __syncthreads();
    int woff = 0;
    for (int w = 0; w < wid; ++w) woff += wsum[w];
    int run = bsum[blockIdx.x] + woff + (x - t);
#pragma unroll
    for (int j = 0; j < 8; ++j) {
        int idx = base + j;
        if (idx < N) {
            rp[idx] = run;
            cur[idx] = run;
            dis[idx] = rsqrtf((float)v[j] + 1.0f);
        }
        run += v[j];
    }
}

// XCD-sliced direct CSR placement; nt loads keep the edge stream from
// evicting the slice's dirty csrc/cur lines out of L2.
// ce is rounded UP to a multiple of 4 so PM chunks always cover all E edges.
__global__ __launch_bounds__(256) void k_place_direct(
        const int* __restrict__ src, const int* __restrict__ dst,
        int* __restrict__ cur, int* __restrict__ csrc, int E, int N) {
    const int slice = blockIdx.x % NXCD;
    const int chunk = blockIdx.x / NXCD;
    const int ns = div_up(N, NXCD);
    const int lo = slice * ns;
    const int hi = min(N, lo + ns);
    const int ce = (div_up(E, PM) + 3) & ~3;      // chunk edges, mult of 4, covers E
    const int e0 = chunk * ce;
    const int e1 = min(E, e0 + ce);
    int i = e0 + threadIdx.x * 4;
    for (; i + 3 < e1; i += 256 * 4) {
        int4v d4 = nt_load4(dst + i);
        int4v s4 = nt_load4(src + i);
        if (d4.x >= lo && d4.x < hi) csrc[atomicAdd(&cur[d4.x], 1)] = s4.x;
        if (d4.y >= lo && d4.y < hi) csrc[atomicAdd(&cur[d4.y], 1)] = s4.y;
        if (d4.z >= lo && d4.z < hi) csrc[atomicAdd(&cur[d4.z], 1)] = s4.z;
        if (d4.w >= lo && d4.w < hi) csrc[atomicAdd(&cur[d4.w], 1)] = s4.w;
    }
    for (int j = i; j < e1; ++j) {
        int d = dst[j];
        if (d >= lo && d < hi) csrc[atomicAdd(&cur[d], 1)] = src[j];
    }
}

// ---------------- propagation ----------------

// F=64: one wave per node; 4 edge-slots x 16 feature-lanes, shfl-reduce across
// slots. Removes the max-of-4-degrees intra-wave imbalance of the packed form.
__global__ __launch_bounds__(256) void k_prop64(const int* __restrict__ rp,
                                                const int* __restrict__ csrc,
                                                const float* __restrict__ dis,
                                                const float* __restrict__ hin,
                                                float* __restrict__ hout, int N) {
    int n = blockIdx.x * 4 + (threadIdx.x >> 6);
    if (n >= N) return;
    int lane = threadIdx.x & 63;
    int es = lane >> 4;       // edge slot 0..3
    int fl = lane & 15;       // feature lane (float4 chunk)
    float dn = dis[n];
    float4 acc = make_float4(0.f, 0.f, 0.f, 0.f);
    if (es == 0) {
        float4 v = *reinterpret_cast<const float4*>(hin + (size_t)n * 64 + 4 * fl);
        float wn = dn * dn;
        acc.x = wn * v.x; acc.y = wn * v.y; acc.z = wn * v.z; acc.w = wn * v.w;
    }
    int e = rp[n] + es, end = rp[n + 1];
    for (; e < end; e += 4) {
        int s = nt_load1(csrc + e);
        float w = dis[s] * dn;
        float4 v = *reinterpret_cast<const float4*>(hin + (size_t)s * 64 + 4 * fl);
        acc.x += w * v.x; acc.y += w * v.y; acc.z += w * v.z; acc.w += w * v.w;
    }
    // reduce across the 4 edge slots
#pragma unroll
    for (int off = 16; off <= 32; off <<= 1) {
        acc.x += __shfl_xor(acc.x, off);
        acc.y += __shfl_xor(acc.y, off);
        acc.z += __shfl_xor(acc.z, off);
        acc.w += __shfl_xor(acc.w, off);
    }
    if (es == 0)
        *reinterpret_cast<float4*>(hout + (size_t)n * 64 + 4 * fl) = acc;
}

// F=40 packed gather (TPE=10 lanes per node).
template<int F>
__global__ void k_prop_gather(const int* __restrict__ rp, const int* __restrict__ csrc,
                              const float* __restrict__ dis,
                              const float* __restrict__ hin, float* __restrict__ hout, int N) {
    constexpr int TPE = F / 4;
    int t = blockIdx.x * blockDim.x + threadIdx.x;
    int n = t / TPE;
    if (n >= N) return;
    int l = t % TPE;
    float dn = dis[n];
    float4 acc = *reinterpret_cast<const float4*>(hin + (size_t)n * F + 4 * l);
    float wn = dn * dn;
    acc.x *= wn; acc.y *= wn; acc.z *= wn; acc.w *= wn;
    int e = rp[n], end = rp[n + 1];
    for (; e + 3 < end; e += 4) {
        int s0 = nt_load1(csrc + e),     s1 = nt_load1(csrc + e + 1);
        int s2 = nt_load1(csrc + e + 2), s3 = nt_load1(csrc + e + 3);
        float w0 = dis[s0] * dn, w1 = dis[s1] * dn;
        float w2 = dis[s2] * dn, w3 = dis[s3] * dn;
        float4 v0 = *reinterpret_cast<const float4*>(hin + (size_t)s0 * F + 4 * l);
        float4 v1 = *reinterpret_cast<const float4*>(hin + (size_t)s1 * F + 4 * l);
        float4 v2 = *reinterpret_cast<const float4*>(hin + (size_t)s2 * F + 4 * l);
        float4 v3 = *reinterpret_cast<const float4*>(hin + (size_t)s3 * F + 4 * l);
        acc.x += w0 * v0.x + w1 * v1.x + w2 * v2.x + w3 * v3.x;
        acc.y += w0 * v0.y + w1 * v1.y + w2 * v2.y + w3 * v3.y;
        acc.z += w0 * v0.z + w1 * v1.z + w2 * v2.z + w3 * v3.z;
        acc.w += w0 * v0.w + w1 * v1.w + w2 * v2.w + w3 * v3.w;
    }
    for (; e < end; ++e) {
        int s0 = csrc[e];
        float w0 = dis[s0] * dn;
        float4 v0 = *reinterpret_cast<const float4*>(hin + (size_t)s0 * F + 4 * l);
        acc.x += w0 * v0.x; acc.y += w0 * v0.y; acc.z += w0 * v0.z; acc.w += w0 * v0.w;
    }
    *reinterpret_cast<float4*>(hout + (size_t)n * F + 4 * l) = acc;
}

// ---------------- dense layers (register-tiled) ----------------

#define FMA4(a, s, v) { (a).x += (s) * (v).x; (a).y += (s) * (v).y; \
                        (a).z += (s) * (v).z; (a).w += (s) * (v).w; }

// Y[n,h] = X[n,:128] @ W[:,h].  Tile: 64 nodes x 64 h, 4x4 per thread.
__global__ __launch_bounds__(256) void k_gemm1(const float* __restrict__ X,
                                               const float* __restrict__ W,
                                               float* __restrict__ Y, int N) {
    __shared__ float sx[64][132];
    __shared__ float sw[128][68];
    const int tid = threadIdx.x;
    const int n0 = blockIdx.x * 64;
    const bool full = (n0 + 64 <= N);
#pragma unroll
    for (int j = 0; j < 8; ++j) {
        int idx = (tid + j * 256) * 4;
        int k = idx >> 6, h = idx & 63;
        *reinterpret_cast<float4*>(&sw[k][h]) = *reinterpret_cast<const float4*>(W + idx);
    }
#pragma unroll
    for (int j = 0; j < 8; ++j) {
        int idx = (tid + j * 256) * 4;
        int n = idx >> 7, k = idx & 127;
        float4 v = make_float4(0.f, 0.f, 0.f, 0.f);
        if (full || n0 + n < N)
            v = *reinterpret_cast<const float4*>(X + (size_t)(n0 + n) * 128 + k);
        *reinterpret_cast<float4*>(&sx[n][k]) = v;
    }
    __syncthreads();
    const int lane = tid & 63, wid = tid >> 6;
    const int h0 = (lane & 15) * 4;
    const int nb = wid * 16 + (lane >> 4) * 4;
    float4 a0 = {0,0,0,0}, a1 = {0,0,0,0}, a2 = {0,0,0,0}, a3 = {0,0,0,0};
#pragma unroll 4
    for (int k0 = 0; k0 < 128; k0 += 4) {
        float4 x0 = *reinterpret_cast<float4*>(&sx[nb + 0][k0]);
        float4 x1 = *reinterpret_cast<float4*>(&sx[nb + 1][k0]);
        float4 x2 = *reinterpret_cast<float4*>(&sx[nb + 2][k0]);
        float4 x3 = *reinterpret_cast<float4*>(&sx[nb + 3][k0]);
        float4 w0 = *reinterpret_cast<float4*>(&sw[k0 + 0][h0]);
        float4 w1 = *reinterpret_cast<float4*>(&sw[k0 + 1][h0]);
        float4 w2 = *reinterpret_cast<float4*>(&sw[k0 + 2][h0]);
        float4 w3 = *reinterpret_cast<float4*>(&sw[k0 + 3][h0]);
        FMA4(a0, x0.x, w0); FMA4(a0, x0.y, w1); FMA4(a0, x0.z, w2); FMA4(a0, x0.w, w3);
        FMA4(a1, x1.x, w0); FMA4(a1, x1.y, w1); FMA4(a1, x1.z, w2); FMA4(a1, x1.w, w3);
        FMA4(a2, x2.x, w0); FMA4(a2, x2.y, w1); FMA4(a2, x2.z, w2); FMA4(a2, x2.w, w3);
        FMA4(a3, x3.x, w0); FMA4(a3, x3.y, w1); FMA4(a3, x3.z, w2); FMA4(a3, x3.w, w3);
    }
    int n = n0 + nb;
    if (n + 0 < N) *reinterpret_cast<float4*>(Y + (size_t)(n + 0) * 64 + h0) = a0;
    if (n + 1 < N) *reinterpret_cast<float4*>(Y + (size_t)(n + 1) * 64 + h0) = a1;
    if (n + 2 < N) *reinterpret_cast<float4*>(Y + (size_t)(n + 2) * 64 + h0) = a2;
    if (n + 3 < N) *reinterpret_cast<float4*>(Y + (size_t)(n + 3) * 64 + h0) = a3;
}

// T[n,c] = relu(H[n,:64]+b1) @ W2[:,c], c < 40 (padded to 64 zero cols).
__global__ __launch_bounds__(256) void k_gemm2(const float* __restrict__ H,
                                               const float* __restrict__ b1,
                                               const float* __restrict__ W2,
                                               float* __restrict__ T, int N) {
    __shared__ float sh[64][68];
    __shared__ float sw[64][68];
    const int tid = threadIdx.x;
    const int n0 = blockIdx.x * 64;
    const bool full = (n0 + 64 <= N);
#pragma unroll
    for (int j = 0; j < 4; ++j) {
        int idx = (tid + j * 256) * 4;
        int k = idx >> 6, h = idx & 63;
        float4 v = make_float4(0.f, 0.f, 0.f, 0.f);
        if (h < 40) v = *reinterpret_cast<const float4*>(W2 + k * 40 + h);
        *reinterpret_cast<float4*>(&sw[k][h]) = v;
    }
#pragma unroll
    for (int j = 0; j < 4; ++j) {
        int idx = (tid + j * 256) * 4;
        int n = idx >> 6, k = idx & 63;
        float4 v = make_float4(0.f, 0.f, 0.f, 0.f);
        if (full || n0 + n < N) {
            float4 hv = *reinterpret_cast<const float4*>(H + (size_t)(n0 + n) * 64 + k);
            float4 bv = *reinterpret_cast<const float4*>(b1 + k);
            v.x = fmaxf(hv.x + bv.x, 0.f); v.y = fmaxf(hv.y + bv.y, 0.f);
            v.z = fmaxf(hv.z + bv.z, 0.f); v.w = fmaxf(hv.w + bv.w, 0.f);
        }
        *reinterpret_cast<float4*>(&sh[n][k]) = v;
    }
    __syncthreads();
    const int lane = tid & 63, wid = tid >> 6;
    const int h0 = (lane & 15) * 4;
    const int nb = wid * 16 + (lane >> 4) * 4;
    float4 a0 = {0,0,0,0}, a1 = {0,0,0,0}, a2 = {0,0,0,0}, a3 = {0,0,0,0};
#pragma unroll 4
    for (int k0 = 0; k0 < 64; k0 += 4) {
        float4 x0 = *reinterpret_cast<float4*>(&sh[nb + 0][k0]);
        float4 x1 = *reinterpret_cast<float4*>(&sh[nb + 1][k0]);
        float4 x2 = *reinterpret_cast<float4*>(&sh[nb + 2][k0]);
        float4 x3 = *reinterpret_cast<float4*>(&sh[nb + 3][k0]);
        float4 w0 = *reinterpret_cast<float4*>(&sw[k0 + 0][h0]);
        float4 w1 = *reinterpret_cast<float4*>(&sw[k0 + 1][h0]);
        float4 w2 = *reinterpret_cast<float4*>(&sw[k0 + 2][h0]);
        float4 w3 = *reinterpret_cast<float4*>(&sw[k0 + 3][h0]);
        FMA4(a0, x0.x, w0); FMA4(a0, x0.y, w1); FMA4(a0, x0.z, w2); FMA4(a0, x0.w, w3);
        FMA4(a1, x1.x, w0); FMA4(a1, x1.y, w1); FMA4(a1, x1.z, w2); FMA4(a1, x1.w, w3);
        FMA4(a2, x2.x, w0); FMA4(a2, x2.y, w1); FMA4(a2, x2.z, w2); FMA4(a2, x2.w, w3);
        FMA4(a3, x3.x, w0); FMA4(a3, x3.y, w1); FMA4(a3, x3.z, w2); FMA4(a3, x3.w, w3);
    }
    if (h0 < 40) {
        int n = n0 + nb;
        if (n + 0 < N) *reinterpret_cast<float4*>(T + (size_t)(n + 0) * 40 + h0) = a0;
        if (n + 1 < N) *reinterpret_cast<float4*>(T + (size_t)(n + 1) * 40 + h0) = a1;
        if (n + 2 < N) *reinterpret_cast<float4*>(T + (size_t)(n + 2) * 40 + h0) = a2;
        if (n + 3 < N) *reinterpret_cast<float4*>(T + (size_t)(n + 3) * 40 + h0) = a3;
    }
}

// out[n,c] = log_softmax(T[n,:40] + b2)   one wave per node, lanes >= 40 padded
__global__ void k_bias_lsm(const float* __restrict__ T, const float* __restrict__ b2,
                           float* __restrict__ Y, int N) {
    int gid = blockIdx.x * blockDim.x + threadIdx.x;
    int node = gid >> 6;
    int lane = threadIdx.x & 63;
    if (node >= N) return;
    float v = (lane < 40) ? T[(size_t)node * 40 + lane] + b2[lane] : -INFINITY;
    float m = v;
    for (int off = 32; off >= 1; off >>= 1) m = fmaxf(m, __shfl_xor(m, off));
    float ev = (lane < 40) ? expf(v - m) : 0.0f;
    float s = ev;
    for (int off = 32; off >= 1; off >>= 1) s += __shfl_xor(s, off);
    if (lane < 40) Y[(size_t)node * 40 + lane] = v - m - logf(s);
}

// ---------------- launch ----------------

extern "C" void kernel_launch(void* const* d_in, const int* in_sizes, int n_in,
                              void* d_out, int out_size, void* d_ws, size_t ws_size,
                              hipStream_t stream) {
    const float* x  = (const float*)d_in[0];
    const int*   ei = (const int*)d_in[1];
    const float* W1 = (const float*)d_in[2];
    const float* b1 = (const float*)d_in[3];
    const float* W2 = (const float*)d_in[4];
    const float* b2 = (const float*)d_in[5];
    float* out = (float*)d_out;

    const int H = in_sizes[3];            // 64
    const int F = in_sizes[2] / H;        // 128
    const int N = in_sizes[0] / F;        // 100000
    const int E = in_sizes[1] / 2;        // 1600000
    (void)ws_size; (void)n_in; (void)out_size;

    const int* src = ei;
    const int* dst = ei + E;
    const int NSB = div_up(N, SCH);       // scan blocks (49)

    // workspace layout (4-byte elems)
    const int Npad = (N + 256) & ~255;          // covers N+1
    float* dis  = (float*)d_ws;                 // N
    int*   cnt  = (int*)(dis + Npad);           // N
    int*   rp   = cnt + Npad;                   // N+1
    int*   cur  = rp + Npad;                    // N
    int*   bsum = cur + Npad;                   // NSB
    int*   csrc = bsum + ((NSB + 255) & ~255);  // E
    float* bufA = (float*)(csrc + ((E + 255) & ~255));   // N*64
    float* bufB = bufA + (size_t)N * 64;                 // N*64

    const int B = 256;

    // ---- CSR build ----
    k_zero_i32<<<div_up(N, B), B, 0, stream>>>(cnt, N);
    k_cnt<<<div_up(E, B * 4), B, 0, stream>>>(dst, cnt, E);
    k_scan_part<<<NSB, 256, 0, stream>>>(cnt, bsum, N);
    k_scan_bsums<<<1, 1024, 0, stream>>>(bsum, rp + N, NSB);
    k_scan_apply<<<NSB, 256, 0, stream>>>(cnt, bsum, rp, cur, dis, N);
    k_place_direct<<<NXCD * PM, 256, 0, stream>>>(src, dst, cur, csrc, E, N);

    // ---- layer 1 (commuted): Y0 = X @ W1, then 2 props at F=64 ----
    k_gemm1<<<div_up(N, 64), 256, 0, stream>>>(x, W1, bufA, N);
    k_prop64<<<div_up(N, 4), 256, 0, stream>>>(rp, csrc, dis, bufA, bufB, N);
    k_prop64<<<div_up(N, 4), 256, 0, stream>>>(rp, csrc, dis, bufB, bufA, N);

    // ---- layer 2 (commuted): T = relu(h + b1) @ W2, then 2 props at F=40 ----
    k_gemm2<<<div_up(N, 64), 256, 0, stream>>>(bufA, b1, W2, bufB, N);
    k_prop_gather<40><<<div_up((long long)N * 10, B), B, 0, stream>>>(rp, csrc, dis, bufB, bufA, N);
    k_prop_gather<40><<<div_up((long long)N * 10, B), B, 0, stream>>>(rp, csrc, dis, bufA, bufB, N);

    // ---- epilogue: out = log_softmax(T + b2) ----
    k_bias_lsm<<<div_up((long long)N * 64, 256), 256, 0, stream>>>(bufB, b2, out, N);
}

// Round 11
// 468.964 us; speedup vs baseline: 1.0713x; 1.0713x over previous
//
#include <hip/hip_runtime.h>
#include <math.h>

__host__ __device__ static inline int div_up(long long a, long long b) { return (int)((a + b - 1) / b); }

#define SCH 2048              // scan chunk per block
#define NXCD 8                // XCD slices for false-sharing-free placement
#define PM 256                // edge chunks for k_place_direct (grid = 8*PM)

typedef int int4v __attribute__((ext_vector_type(4)));

__device__ inline int4v nt_load4(const int* p) {
    return __builtin_nontemporal_load(reinterpret_cast<const int4v*>(p));
}
__device__ inline int nt_load1(const int* p) {
    return __builtin_nontemporal_load(p);
}

// ---------------- CSR build ----------------

__global__ void k_zero_i32(int* __restrict__ p, int n) {
    int i = blockIdx.x * blockDim.x + threadIdx.x;
    if (i < n) p[i] = 0;
}

__global__ void k_cnt(const int* __restrict__ dst, int* __restrict__ cnt, int E) {
    int i = (blockIdx.x * blockDim.x + threadIdx.x) * 4;
    if (i + 3 < E) {
        int4v d = nt_load4(dst + i);
        atomicAdd(&cnt[d.x], 1);
        atomicAdd(&cnt[d.y], 1);
        atomicAdd(&cnt[d.z], 1);
        atomicAdd(&cnt[d.w], 1);
    } else {
        for (int j = i; j < E; ++j) atomicAdd(&cnt[dst[j]], 1);
    }
}

// Phase 1: per-block sums of SCH-element chunks.
__global__ void k_scan_part(const int* __restrict__ cnt, int* __restrict__ bsum, int N) {
    __shared__ int ws[4];
    int base = blockIdx.x * SCH + threadIdx.x * 8;
    int t = 0;
#pragma unroll
    for (int j = 0; j < 8; ++j) {
        int idx = base + j;
        if (idx < N) t += cnt[idx];
    }
    for (int off = 32; off >= 1; off >>= 1) t += __shfl_xor(t, off);
    int lane = threadIdx.x & 63, wid = threadIdx.x >> 6;
    if (lane == 0) ws[wid] = t;
    __syncthreads();
    if (threadIdx.x == 0) bsum[blockIdx.x] = ws[0] + ws[1] + ws[2] + ws[3];
}

// Phase 2: exclusive scan of block sums (NB <= 1024) + grand total -> rpN.
__global__ void k_scan_bsums(int* __restrict__ bsum, int* __restrict__ rpN, int NB) {
    __shared__ int wsum[16];
    int tid = threadIdx.x;
    int v = (tid < NB) ? bsum[tid] : 0;
    int lane = tid & 63, wid = tid >> 6;
    int x = v;
    for (int off = 1; off < 64; off <<= 1) {
        int y = __shfl_up(x, off);
        if (lane >= off) x += y;
    }
    if (lane == 63) wsum[wid] = x;
    __syncthreads();
    if (tid < 16) {
        int s = wsum[tid];
        for (int off = 1; off < 16; off <<= 1) {
            int y = __shfl_up(s, off);
            if (tid >= off) s += y;
        }
        wsum[tid] = s;
    }
    __syncthreads();
    int woff = (wid > 0) ? wsum[wid - 1] : 0;
    int excl = woff + x - v;
    if (tid < NB) bsum[tid] = excl;
    if (tid == NB - 1) rpN[0] = excl + v;
}

// Phase 3: local exclusive scan + block offset; emits rp, cur, dis.
__global__ void k_scan_apply(const int* __restrict__ cnt, const int* __restrict__ bsum,
                             int* __restrict__ rp, int* __restrict__ cur,
                             float* __restrict__ dis, int N) {
    __shared__ int wsum[4];
    int tid = threadIdx.x;
    int base = blockIdx.x * SCH + tid * 8;
    int v[8];
    int t = 0;
#pragma unroll
    for (int j = 0; j < 8; ++j) {
        int idx = base + j;
        v[j] = (idx < N) ? cnt[idx] : 0;
        t += v[j];
    }
    int lane = tid & 63, wid = tid >> 6;
    int x = t;
    for (int off = 1; off < 64; off <<= 1) {
        int y = __shfl_up(x, off);
        if (lane >= off) x += y;
    }
    if (lane == 63) wsum[wid] = x;
    __syncthreads();
    int woff = 0;
    for (int w = 0; w < wid; ++w) woff += wsum[w];
    int run = bsum[blockIdx.x] + woff + (x - t);
#pragma unroll
    for (int j = 0; j < 8; ++j) {
        int idx = base + j;
        if (idx < N) {
            rp[idx] = run;
            cur[idx] = run;
            dis[idx] = rsqrtf((float)v[j] + 1.0f);
        }
        run += v[j];
    }
}

// XCD-sliced direct CSR placement; nt loads keep the edge stream from
// evicting the slice's dirty csrc/cur lines out of L2.
// ce is rounded UP to a multiple of 4 so PM chunks always cover all E edges.
__global__ __launch_bounds__(256) void k_place_direct(
        const int* __restrict__ src, const int* __restrict__ dst,
        int* __restrict__ cur, int* __restrict__ csrc, int E, int N) {
    const int slice = blockIdx.x % NXCD;
    const int chunk = blockIdx.x / NXCD;
    const int ns = div_up(N, NXCD);
    const int lo = slice * ns;
    const int hi = min(N, lo + ns);
    const int ce = (div_up(E, PM) + 3) & ~3;      // chunk edges, mult of 4, covers E
    const int e0 = chunk * ce;
    const int e1 = min(E, e0 + ce);
    int i = e0 + threadIdx.x * 4;
    for (; i + 3 < e1; i += 256 * 4) {
        int4v d4 = nt_load4(dst + i);
        int4v s4 = nt_load4(src + i);
        if (d4.x >= lo && d4.x < hi) csrc[atomicAdd(&cur[d4.x], 1)] = s4.x;
        if (d4.y >= lo && d4.y < hi) csrc[atomicAdd(&cur[d4.y], 1)] = s4.y;
        if (d4.z >= lo && d4.z < hi) csrc[atomicAdd(&cur[d4.z], 1)] = s4.z;
        if (d4.w >= lo && d4.w < hi) csrc[atomicAdd(&cur[d4.w], 1)] = s4.w;
    }
    for (int j = i; j < e1; ++j) {
        int d = dst[j];
        if (d >= lo && d < hi) csrc[atomicAdd(&cur[d], 1)] = src[j];
    }
}

// ---------------- propagation: h_out = A_hat_norm @ h_in (gather form) ----------------
// Packed: TPE = F/4 lanes per node. Edge loop unrolled 8-deep to maximize
// outstanding row-gathers (latency-bound regime — MLP is the lever, r10 lesson).

template<int F>
__global__ __launch_bounds__(256) void k_prop_gather(
        const int* __restrict__ rp, const int* __restrict__ csrc,
        const float* __restrict__ dis,
        const float* __restrict__ hin, float* __restrict__ hout, int N) {
    constexpr int TPE = F / 4;
    int t = blockIdx.x * blockDim.x + threadIdx.x;
    int n = t / TPE;
    if (n >= N) return;
    int l = t % TPE;
    float dn = dis[n];
    float4 acc = *reinterpret_cast<const float4*>(hin + (size_t)n * F + 4 * l);
    float wn = dn * dn;
    acc.x *= wn; acc.y *= wn; acc.z *= wn; acc.w *= wn;
    int e = rp[n], end = rp[n + 1];
    for (; e + 7 < end; e += 8) {
        int s[8];
        float w[8];
        float4 v[8];
#pragma unroll
        for (int j = 0; j < 8; ++j) s[j] = nt_load1(csrc + e + j);
#pragma unroll
        for (int j = 0; j < 8; ++j) w[j] = dis[s[j]] * dn;
#pragma unroll
        for (int j = 0; j < 8; ++j)
            v[j] = *reinterpret_cast<const float4*>(hin + (size_t)s[j] * F + 4 * l);
#pragma unroll
        for (int j = 0; j < 8; ++j) {
            acc.x += w[j] * v[j].x; acc.y += w[j] * v[j].y;
            acc.z += w[j] * v[j].z; acc.w += w[j] * v[j].w;
        }
    }
    for (; e + 3 < end; e += 4) {
        int s0 = nt_load1(csrc + e),     s1 = nt_load1(csrc + e + 1);
        int s2 = nt_load1(csrc + e + 2), s3 = nt_load1(csrc + e + 3);
        float w0 = dis[s0] * dn, w1 = dis[s1] * dn;
        float w2 = dis[s2] * dn, w3 = dis[s3] * dn;
        float4 v0 = *reinterpret_cast<const float4*>(hin + (size_t)s0 * F + 4 * l);
        float4 v1 = *reinterpret_cast<const float4*>(hin + (size_t)s1 * F + 4 * l);
        float4 v2 = *reinterpret_cast<const float4*>(hin + (size_t)s2 * F + 4 * l);
        float4 v3 = *reinterpret_cast<const float4*>(hin + (size_t)s3 * F + 4 * l);
        acc.x += w0 * v0.x + w1 * v1.x + w2 * v2.x + w3 * v3.x;
        acc.y += w0 * v0.y + w1 * v1.y + w2 * v2.y + w3 * v3.y;
        acc.z += w0 * v0.z + w1 * v1.z + w2 * v2.z + w3 * v3.z;
        acc.w += w0 * v0.w + w1 * v1.w + w2 * v2.w + w3 * v3.w;
    }
    for (; e < end; ++e) {
        int s0 = csrc[e];
        float w0 = dis[s0] * dn;
        float4 v0 = *reinterpret_cast<const float4*>(hin + (size_t)s0 * F + 4 * l);
        acc.x += w0 * v0.x; acc.y += w0 * v0.y; acc.z += w0 * v0.z; acc.w += w0 * v0.w;
    }
    *reinterpret_cast<float4*>(hout + (size_t)n * F + 4 * l) = acc;
}

// ---------------- dense layers (register-tiled) ----------------

#define FMA4(a, s, v) { (a).x += (s) * (v).x; (a).y += (s) * (v).y; \
                        (a).z += (s) * (v).z; (a).w += (s) * (v).w; }

// Y[n,h] = X[n,:128] @ W[:,h].  Tile: 64 nodes x 64 h, 4x4 per thread.
__global__ __launch_bounds__(256) void k_gemm1(const float* __restrict__ X,
                                               const float* __restrict__ W,
                                               float* __restrict__ Y, int N) {
    __shared__ float sx[64][132];
    __shared__ float sw[128][68];
    const int tid = threadIdx.x;
    const int n0 = blockIdx.x * 64;
    const bool full = (n0 + 64 <= N);
#pragma unroll
    for (int j = 0; j < 8; ++j) {
        int idx = (tid + j * 256) * 4;
        int k = idx >> 6, h = idx & 63;
        *reinterpret_cast<float4*>(&sw[k][h]) = *reinterpret_cast<const float4*>(W + idx);
    }
#pragma unroll
    for (int j = 0; j < 8; ++j) {
        int idx = (tid + j * 256) * 4;
        int n = idx >> 7, k = idx & 127;
        float4 v = make_float4(0.f, 0.f, 0.f, 0.f);
        if (full || n0 + n < N)
            v = *reinterpret_cast<const float4*>(X + (size_t)(n0 + n) * 128 + k);
        *reinterpret_cast<float4*>(&sx[n][k]) = v;
    }
    __syncthreads();
    const int lane = tid & 63, wid = tid >> 6;
    const int h0 = (lane & 15) * 4;
    const int nb = wid * 16 + (lane >> 4) * 4;
    float4 a0 = {0,0,0,0}, a1 = {0,0,0,0}, a2 = {0,0,0,0}, a3 = {0,0,0,0};
#pragma unroll 4
    for (int k0 = 0; k0 < 128; k0 += 4) {
        float4 x0 = *reinterpret_cast<float4*>(&sx[nb + 0][k0]);
        float4 x1 = *reinterpret_cast<float4*>(&sx[nb + 1][k0]);
        float4 x2 = *reinterpret_cast<float4*>(&sx[nb + 2][k0]);
        float4 x3 = *reinterpret_cast<float4*>(&sx[nb + 3][k0]);
        float4 w0 = *reinterpret_cast<float4*>(&sw[k0 + 0][h0]);
        float4 w1 = *reinterpret_cast<float4*>(&sw[k0 + 1][h0]);
        float4 w2 = *reinterpret_cast<float4*>(&sw[k0 + 2][h0]);
        float4 w3 = *reinterpret_cast<float4*>(&sw[k0 + 3][h0]);
        FMA4(a0, x0.x, w0); FMA4(a0, x0.y, w1); FMA4(a0, x0.z, w2); FMA4(a0, x0.w, w3);
        FMA4(a1, x1.x, w0); FMA4(a1, x1.y, w1); FMA4(a1, x1.z, w2); FMA4(a1, x1.w, w3);
        FMA4(a2, x2.x, w0); FMA4(a2, x2.y, w1); FMA4(a2, x2.z, w2); FMA4(a2, x2.w, w3);
        FMA4(a3, x3.x, w0); FMA4(a3, x3.y, w1); FMA4(a3, x3.z, w2); FMA4(a3, x3.w, w3);
    }
    int n = n0 + nb;
    if (n + 0 < N) *reinterpret_cast<float4*>(Y + (size_t)(n + 0) * 64 + h0) = a0;
    if (n + 1 < N) *reinterpret_cast<float4*>(Y + (size_t)(n + 1) * 64 + h0) = a1;
    if (n + 2 < N) *reinterpret_cast<float4*>(Y + (size_t)(n + 2) * 64 + h0) = a2;
    if (n + 3 < N) *reinterpret_cast<float4*>(Y + (size_t)(n + 3) * 64 + h0) = a3;
}

// T[n,c] = relu(H[n,:64]+b1) @ W2[:,c], c < 40 (padded to 64 zero cols).
__global__ __launch_bounds__(256) void k_gemm2(const float* __restrict__ H,
                                               const float* __restrict__ b1,
                                               const float* __restrict__ W2,
                                               float* __restrict__ T, int N) {
    __shared__ float sh[64][68];
    __shared__ float sw[64][68];
    const int tid = threadIdx.x;
    const int n0 = blockIdx.x * 64;
    const bool full = (n0 + 64 <= N);
#pragma unroll
    for (int j = 0; j < 4; ++j) {
        int idx = (tid + j * 256) * 4;
        int k = idx >> 6, h = idx & 63;
        float4 v = make_float4(0.f, 0.f, 0.f, 0.f);
        if (h < 40) v = *reinterpret_cast<const float4*>(W2 + k * 40 + h);
        *reinterpret_cast<float4*>(&sw[k][h]) = v;
    }
#pragma unroll
    for (int j = 0; j < 4; ++j) {
        int idx = (tid + j * 256) * 4;
        int n = idx >> 6, k = idx & 63;
        float4 v = make_float4(0.f, 0.f, 0.f, 0.f);
        if (full || n0 + n < N) {
            float4 hv = *reinterpret_cast<const float4*>(H + (size_t)(n0 + n) * 64 + k);
            float4 bv = *reinterpret_cast<const float4*>(b1 + k);
            v.x = fmaxf(hv.x + bv.x, 0.f); v.y = fmaxf(hv.y + bv.y, 0.f);
            v.z = fmaxf(hv.z + bv.z, 0.f); v.w = fmaxf(hv.w + bv.w, 0.f);
        }
        *reinterpret_cast<float4*>(&sh[n][k]) = v;
    }
    __syncthreads();
    const int lane = tid & 63, wid = tid >> 6;
    const int h0 = (lane & 15) * 4;
    const int nb = wid * 16 + (lane >> 4) * 4;
    float4 a0 = {0,0,0,0}, a1 = {0,0,0,0}, a2 = {0,0,0,0}, a3 = {0,0,0,0};
#pragma unroll 4
    for (int k0 = 0; k0 < 64; k0 += 4) {
        float4 x0 = *reinterpret_cast<float4*>(&sh[nb + 0][k0]);
        float4 x1 = *reinterpret_cast<float4*>(&sh[nb + 1][k0]);
        float4 x2 = *reinterpret_cast<float4*>(&sh[nb + 2][k0]);
        float4 x3 = *reinterpret_cast<float4*>(&sh[nb + 3][k0]);
        float4 w0 = *reinterpret_cast<float4*>(&sw[k0 + 0][h0]);
        float4 w1 = *reinterpret_cast<float4*>(&sw[k0 + 1][h0]);
        float4 w2 = *reinterpret_cast<float4*>(&sw[k0 + 2][h0]);
        float4 w3 = *reinterpret_cast<float4*>(&sw[k0 + 3][h0]);
        FMA4(a0, x0.x, w0); FMA4(a0, x0.y, w1); FMA4(a0, x0.z, w2); FMA4(a0, x0.w, w3);
        FMA4(a1, x1.x, w0); FMA4(a1, x1.y, w1); FMA4(a1, x1.z, w2); FMA4(a1, x1.w, w3);
        FMA4(a2, x2.x, w0); FMA4(a2, x2.y, w1); FMA4(a2, x2.z, w2); FMA4(a2, x2.w, w3);
        FMA4(a3, x3.x, w0); FMA4(a3, x3.y, w1); FMA4(a3, x3.z, w2); FMA4(a3, x3.w, w3);
    }
    if (h0 < 40) {
        int n = n0 + nb;
        if (n + 0 < N) *reinterpret_cast<float4*>(T + (size_t)(n + 0) * 40 + h0) = a0;
        if (n + 1 < N) *reinterpret_cast<float4*>(T + (size_t)(n + 1) * 40 + h0) = a1;
        if (n + 2 < N) *reinterpret_cast<float4*>(T + (size_t)(n + 2) * 40 + h0) = a2;
        if (n + 3 < N) *reinterpret_cast<float4*>(T + (size_t)(n + 3) * 40 + h0) = a3;
    }
}

// out[n,c] = log_softmax(T[n,:40] + b2)   one wave per node, lanes >= 40 padded
__global__ void k_bias_lsm(const float* __restrict__ T, const float* __restrict__ b2,
                           float* __restrict__ Y, int N) {
    int gid = blockIdx.x * blockDim.x + threadIdx.x;
    int node = gid >> 6;
    int lane = threadIdx.x & 63;
    if (node >= N) return;
    float v = (lane < 40) ? T[(size_t)node * 40 + lane] + b2[lane] : -INFINITY;
    float m = v;
    for (int off = 32; off >= 1; off >>= 1) m = fmaxf(m, __shfl_xor(m, off));
    float ev = (lane < 40) ? expf(v - m) : 0.0f;
    float s = ev;
    for (int off = 32; off >= 1; off >>= 1) s += __shfl_xor(s, off);
    if (lane < 40) Y[(size_t)node * 40 + lane] = v - m - logf(s);
}

// ---------------- launch ----------------

extern "C" void kernel_launch(void* const* d_in, const int* in_sizes, int n_in,
                              void* d_out, int out_size, void* d_ws, size_t ws_size,
                              hipStream_t stream) {
    const float* x  = (const float*)d_in[0];
    const int*   ei = (const int*)d_in[1];
    const float* W1 = (const float*)d_in[2];
    const float* b1 = (const float*)d_in[3];
    const float* W2 = (const float*)d_in[4];
    const float* b2 = (const float*)d_in[5];
    float* out = (float*)d_out;

    const int H = in_sizes[3];            // 64
    const int F = in_sizes[2] / H;        // 128
    const int N = in_sizes[0] / F;        // 100000
    const int E = in_sizes[1] / 2;        // 1600000
    (void)ws_size; (void)n_in; (void)out_size;

    const int* src = ei;
    const int* dst = ei + E;
    const int NSB = div_up(N, SCH);       // scan blocks (49)

    // workspace layout (4-byte elems)
    const int Npad = (N + 256) & ~255;          // covers N+1
    float* dis  = (float*)d_ws;                 // N
    int*   cnt  = (int*)(dis + Npad);           // N
    int*   rp   = cnt + Npad;                   // N+1
    int*   cur  = rp + Npad;                    // N
    int*   bsum = cur + Npad;                   // NSB
    int*   csrc = bsum + ((NSB + 255) & ~255);  // E
    float* bufA = (float*)(csrc + ((E + 255) & ~255));   // N*64
    float* bufB = bufA + (size_t)N * 64;                 // N*64

    const int B = 256;

    // ---- CSR build ----
    k_zero_i32<<<div_up(N, B), B, 0, stream>>>(cnt, N);
    k_cnt<<<div_up(E, B * 4), B, 0, stream>>>(dst, cnt, E);
    k_scan_part<<<NSB, 256, 0, stream>>>(cnt, bsum, N);
    k_scan_bsums<<<1, 1024, 0, stream>>>(bsum, rp + N, NSB);
    k_scan_apply<<<NSB, 256, 0, stream>>>(cnt, bsum, rp, cur, dis, N);
    k_place_direct<<<NXCD * PM, 256, 0, stream>>>(src, dst, cur, csrc, E, N);

    // ---- layer 1 (commuted): Y0 = X @ W1, then 2 props at F=64 ----
    k_gemm1<<<div_up(N, 64), 256, 0, stream>>>(x, W1, bufA, N);
    k_prop_gather<64><<<div_up((long long)N * 16, B), B, 0, stream>>>(rp, csrc, dis, bufA, bufB, N);
    k_prop_gather<64><<<div_up((long long)N * 16, B), B, 0, stream>>>(rp, csrc, dis, bufB, bufA, N);

    // ---- layer 2 (commuted): T = relu(h + b1) @ W2, then 2 props at F=40 ----
    k_gemm2<<<div_up(N, 64), 256, 0, stream>>>(bufA, b1, W2, bufB, N);
    k_prop_gather<40><<<div_up((long long)N * 10, B), B, 0, stream>>>(rp, csrc, dis, bufB, bufA, N);
    k_prop_gather<40><<<div_up((long long)N * 10, B), B, 0, stream>>>(rp, csrc, dis, bufA, bufB, N);

    // ---- epilogue: out = log_softmax(T + b2) ----
    k_bias_lsm<<<div_up((long long)N * 64, 256), 256, 0, stream>>>(bufB, b2, out, N);
}

// Round 12
// 404.356 us; speedup vs baseline: 1.2424x; 1.1598x over previous
//
#include <hip/hip_runtime.h>
#include <hip/hip_fp16.h>
#include <math.h>

__host__ __device__ static inline int div_up(long long a, long long b) { return (int)((a + b - 1) / b); }

#define SCH 2048              // scan chunk per block
#define NXCD 8                // XCD slices for false-sharing-free placement
#define PM 256                // edge chunks for k_place_direct (grid = 8*PM)

typedef int int4v __attribute__((ext_vector_type(4)));

struct h8 { __half2 a, b, c, d; };   // 8 halfs = 16 B
struct h4 { __half2 a, b; };         // 4 halfs = 8 B

__device__ inline int4v nt_load4(const int* p) {
    return __builtin_nontemporal_load(reinterpret_cast<const int4v*>(p));
}
__device__ inline int nt_load1(const int* p) {
    return __builtin_nontemporal_load(p);
}

// ---------------- CSR build ----------------

__global__ void k_zero_i32(int* __restrict__ p, int n) {
    int i = blockIdx.x * blockDim.x + threadIdx.x;
    if (i < n) p[i] = 0;
}

__global__ void k_cnt(const int* __restrict__ dst, int* __restrict__ cnt, int E) {
    int i = (blockIdx.x * blockDim.x + threadIdx.x) * 4;
    if (i + 3 < E) {
        int4v d = nt_load4(dst + i);
        atomicAdd(&cnt[d.x], 1);
        atomicAdd(&cnt[d.y], 1);
        atomicAdd(&cnt[d.z], 1);
        atomicAdd(&cnt[d.w], 1);
    } else {
        for (int j = i; j < E; ++j) atomicAdd(&cnt[dst[j]], 1);
    }
}

__global__ void k_scan_part(const int* __restrict__ cnt, int* __restrict__ bsum, int N) {
    __shared__ int ws[4];
    int base = blockIdx.x * SCH + threadIdx.x * 8;
    int t = 0;
#pragma unroll
    for (int j = 0; j < 8; ++j) {
        int idx = base + j;
        if (idx < N) t += cnt[idx];
    }
    for (int off = 32; off >= 1; off >>= 1) t += __shfl_xor(t, off);
    int lane = threadIdx.x & 63, wid = threadIdx.x >> 6;
    if (lane == 0) ws[wid] = t;
    __syncthreads();
    if (threadIdx.x == 0) bsum[blockIdx.x] = ws[0] + ws[1] + ws[2] + ws[3];
}

__global__ void k_scan_bsums(int* __restrict__ bsum, int* __restrict__ rpN, int NB) {
    __shared__ int wsum[16];
    int tid = threadIdx.x;
    int v = (tid < NB) ? bsum[tid] : 0;
    int lane = tid & 63, wid = tid >> 6;
    int x = v;
    for (int off = 1; off < 64; off <<= 1) {
        int y = __shfl_up(x, off);
        if (lane >= off) x += y;
    }
    if (lane == 63) wsum[wid] = x;
    __syncthreads();
    if (tid < 16) {
        int s = wsum[tid];
        for (int off = 1; off < 16; off <<= 1) {
            int y = __shfl_up(s, off);
            if (tid >= off) s += y;
        }
        wsum[tid] = s;
    }
    __syncthreads();
    int woff = (wid > 0) ? wsum[wid - 1] : 0;
    int excl = woff + x - v;
    if (tid < NB) bsum[tid] = excl;
    if (tid == NB - 1) rpN[0] = excl + v;
}

__global__ void k_scan_apply(const int* __restrict__ cnt, const int* __restrict__ bsum,
                             int* __restrict__ rp, int* __restrict__ cur,
                             float* __restrict__ dis, int N) {
    __shared__ int wsum[4];
    int tid = threadIdx.x;
    int base = blockIdx.x * SCH + tid * 8;
    int v[8];
    int t = 0;
#pragma unroll
    for (int j = 0; j < 8; ++j) {
        int idx = base + j;
        v[j] = (idx < N) ? cnt[idx] : 0;
        t += v[j];
    }
    int lane = tid & 63, wid = tid >> 6;
    int x = t;
    for (int off = 1; off < 64; off <<= 1) {
        int y = __shfl_up(x, off);
        if (lane >= off) x += y;
    }
    if (lane == 63) wsum[wid] = x;
    __syncthreads();
    int woff = 0;
    for (int w = 0; w < wid; ++w) woff += wsum[w];
    int run = bsum[blockIdx.x] + woff + (x - t);
#pragma unroll
    for (int j = 0; j < 8; ++j) {
        int idx = base + j;
        if (idx < N) {
            rp[idx] = run;
            cur[idx] = run;
            dis[idx] = rsqrtf((float)v[j] + 1.0f);
        }
        run += v[j];
    }
}

// XCD-sliced direct CSR placement (see r8/r11 notes).
__global__ __launch_bounds__(256) void k_place_direct(
        const int* __restrict__ src, const int* __restrict__ dst,
        int* __restrict__ cur, int* __restrict__ csrc, int E, int N) {
    const int slice = blockIdx.x % NXCD;
    const int chunk = blockIdx.x / NXCD;
    const int ns = div_up(N, NXCD);
    const int lo = slice * ns;
    const int hi = min(N, lo + ns);
    const int ce = (div_up(E, PM) + 3) & ~3;      // mult of 4, covers E
    const int e0 = chunk * ce;
    const int e1 = min(E, e0 + ce);
    int i = e0 + threadIdx.x * 4;
    for (; i + 3 < e1; i += 256 * 4) {
        int4v d4 = nt_load4(dst + i);
        int4v s4 = nt_load4(src + i);
        if (d4.x >= lo && d4.x < hi) csrc[atomicAdd(&cur[d4.x], 1)] = s4.x;
        if (d4.y >= lo && d4.y < hi) csrc[atomicAdd(&cur[d4.y], 1)] = s4.y;
        if (d4.z >= lo && d4.z < hi) csrc[atomicAdd(&cur[d4.z], 1)] = s4.z;
        if (d4.w >= lo && d4.w < hi) csrc[atomicAdd(&cur[d4.w], 1)] = s4.w;
    }
    for (int j = i; j < e1; ++j) {
        int d = dst[j];
        if (d >= lo && d < hi) csrc[atomicAdd(&cur[d], 1)] = src[j];
    }
}

// ---------------- propagation (fp16 rows, fp32 accumulate) ----------------
// TPE = F/8 lanes per node; each lane owns an 8-half (16 B) chunk.
// 8-deep edge unroll for memory-level parallelism (r10/r11 lesson).

__device__ inline void fma_h8(float* acc, float w, const h8& v) {
    float2 f0 = __half22float2(v.a), f1 = __half22float2(v.b);
    float2 f2 = __half22float2(v.c), f3 = __half22float2(v.d);
    acc[0] += w * f0.x; acc[1] += w * f0.y;
    acc[2] += w * f1.x; acc[3] += w * f1.y;
    acc[4] += w * f2.x; acc[5] += w * f2.y;
    acc[6] += w * f3.x; acc[7] += w * f3.y;
}

template<int F>  // F in halfs per row; TPE = F/8
__global__ __launch_bounds__(256) void k_prop_h(
        const int* __restrict__ rp, const int* __restrict__ csrc,
        const float* __restrict__ dis,
        const __half* __restrict__ hin, __half* __restrict__ hout, int N) {
    constexpr int TPE = F / 8;
    int t = blockIdx.x * blockDim.x + threadIdx.x;
    int n = t / TPE;
    if (n >= N) return;
    int l = t % TPE;
    float dn = dis[n];
    float acc[8];
    {
        h8 v = *reinterpret_cast<const h8*>(hin + (size_t)n * F + 8 * l);
        float wn = dn * dn;
#pragma unroll
        for (int j = 0; j < 8; ++j) acc[j] = 0.f;
        fma_h8(acc, wn, v);
    }
    int e = rp[n], end = rp[n + 1];
    for (; e + 7 < end; e += 8) {
        int s[8];
        float w[8];
        h8 v[8];
#pragma unroll
        for (int j = 0; j < 8; ++j) s[j] = nt_load1(csrc + e + j);
#pragma unroll
        for (int j = 0; j < 8; ++j) w[j] = dis[s[j]] * dn;
#pragma unroll
        for (int j = 0; j < 8; ++j)
            v[j] = *reinterpret_cast<const h8*>(hin + (size_t)s[j] * F + 8 * l);
#pragma unroll
        for (int j = 0; j < 8; ++j) fma_h8(acc, w[j], v[j]);
    }
    for (; e < end; ++e) {
        int s = nt_load1(csrc + e);
        float w = dis[s] * dn;
        h8 v = *reinterpret_cast<const h8*>(hin + (size_t)s * F + 8 * l);
        fma_h8(acc, w, v);
    }
    h8 o;
    o.a = __float22half2_rn(make_float2(acc[0], acc[1]));
    o.b = __float22half2_rn(make_float2(acc[2], acc[3]));
    o.c = __float22half2_rn(make_float2(acc[4], acc[5]));
    o.d = __float22half2_rn(make_float2(acc[6], acc[7]));
    *reinterpret_cast<h8*>(hout + (size_t)n * F + 8 * l) = o;
}

// ---------------- dense layers (register-tiled) ----------------

#define FMA4(a, s, v) { (a).x += (s) * (v).x; (a).y += (s) * (v).y; \
                        (a).z += (s) * (v).z; (a).w += (s) * (v).w; }

// Y[n,h] = X[n,:128] @ W[:,h], output fp16. Tile: 64 nodes x 64 h, 4x4/thread.
__global__ __launch_bounds__(256) void k_gemm1(const float* __restrict__ X,
                                               const float* __restrict__ W,
                                               __half* __restrict__ Y, int N) {
    __shared__ float sx[64][132];
    __shared__ float sw[128][68];
    const int tid = threadIdx.x;
    const int n0 = blockIdx.x * 64;
    const bool full = (n0 + 64 <= N);
#pragma unroll
    for (int j = 0; j < 8; ++j) {
        int idx = (tid + j * 256) * 4;
        int k = idx >> 6, h = idx & 63;
        *reinterpret_cast<float4*>(&sw[k][h]) = *reinterpret_cast<const float4*>(W + idx);
    }
#pragma unroll
    for (int j = 0; j < 8; ++j) {
        int idx = (tid + j * 256) * 4;
        int n = idx >> 7, k = idx & 127;
        float4 v = make_float4(0.f, 0.f, 0.f, 0.f);
        if (full || n0 + n < N)
            v = *reinterpret_cast<const float4*>(X + (size_t)(n0 + n) * 128 + k);
        *reinterpret_cast<float4*>(&sx[n][k]) = v;
    }
    __syncthreads();
    const int lane = tid & 63, wid = tid >> 6;
    const int h0 = (lane & 15) * 4;
    const int nb = wid * 16 + (lane >> 4) * 4;
    float4 a0 = {0,0,0,0}, a1 = {0,0,0,0}, a2 = {0,0,0,0}, a3 = {0,0,0,0};
#pragma unroll 4
    for (int k0 = 0; k0 < 128; k0 += 4) {
        float4 x0 = *reinterpret_cast<float4*>(&sx[nb + 0][k0]);
        float4 x1 = *reinterpret_cast<float4*>(&sx[nb + 1][k0]);
        float4 x2 = *reinterpret_cast<float4*>(&sx[nb + 2][k0]);
        float4 x3 = *reinterpret_cast<float4*>(&sx[nb + 3][k0]);
        float4 w0 = *reinterpret_cast<float4*>(&sw[k0 + 0][h0]);
        float4 w1 = *reinterpret_cast<float4*>(&sw[k0 + 1][h0]);
        float4 w2 = *reinterpret_cast<float4*>(&sw[k0 + 2][h0]);
        float4 w3 = *reinterpret_cast<float4*>(&sw[k0 + 3][h0]);
        FMA4(a0, x0.x, w0); FMA4(a0, x0.y, w1); FMA4(a0, x0.z, w2); FMA4(a0, x0.w, w3);
        FMA4(a1, x1.x, w0); FMA4(a1, x1.y, w1); FMA4(a1, x1.z, w2); FMA4(a1, x1.w, w3);
        FMA4(a2, x2.x, w0); FMA4(a2, x2.y, w1); FMA4(a2, x2.z, w2); FMA4(a2, x2.w, w3);
        FMA4(a3, x3.x, w0); FMA4(a3, x3.y, w1); FMA4(a3, x3.z, w2); FMA4(a3, x3.w, w3);
    }
    int n = n0 + nb;
#pragma unroll
    for (int r = 0; r < 4; ++r) {
        float4 a = (r == 0) ? a0 : (r == 1) ? a1 : (r == 2) ? a2 : a3;
        if (n + r < N) {
            h4 o;
            o.a = __float22half2_rn(make_float2(a.x, a.y));
            o.b = __float22half2_rn(make_float2(a.z, a.w));
            *reinterpret_cast<h4*>(Y + (size_t)(n + r) * 64 + h0) = o;
        }
    }
}

// T[n,c] = relu(H[n,:64]+b1) @ W2[:,c]; H fp16 in, T fp16 out (c<40, padded 64).
__global__ __launch_bounds__(256) void k_gemm2(const __half* __restrict__ H,
                                               const float* __restrict__ b1,
                                               const float* __restrict__ W2,
                                               __half* __restrict__ T, int N) {
    __shared__ float sh[64][68];
    __shared__ float sw[64][68];
    const int tid = threadIdx.x;
    const int n0 = blockIdx.x * 64;
    const bool full = (n0 + 64 <= N);
#pragma unroll
    for (int j = 0; j < 4; ++j) {
        int idx = (tid + j * 256) * 4;
        int k = idx >> 6, h = idx & 63;
        float4 v = make_float4(0.f, 0.f, 0.f, 0.f);
        if (h < 40) v = *reinterpret_cast<const float4*>(W2 + k * 40 + h);
        *reinterpret_cast<float4*>(&sw[k][h]) = v;
    }
    // stage relu(H + b1), fp16 -> fp32: each thread loads 8 halfs (16B), 2 iters
#pragma unroll
    for (int j = 0; j < 2; ++j) {
        int idx = (tid + j * 256) * 8;       // half index within tile
        int n = idx >> 6, k = idx & 63;
        float v[8];
        if (full || n0 + n < N) {
            h8 hv = *reinterpret_cast<const h8*>(H + (size_t)(n0 + n) * 64 + k);
            float2 f0 = __half22float2(hv.a), f1 = __half22float2(hv.b);
            float2 f2 = __half22float2(hv.c), f3 = __half22float2(hv.d);
            v[0] = f0.x; v[1] = f0.y; v[2] = f1.x; v[3] = f1.y;
            v[4] = f2.x; v[5] = f2.y; v[6] = f3.x; v[7] = f3.y;
#pragma unroll
            for (int q = 0; q < 8; ++q) v[q] = fmaxf(v[q] + b1[k + q], 0.f);
        } else {
#pragma unroll
            for (int q = 0; q < 8; ++q) v[q] = 0.f;
        }
#pragma unroll
        for (int q = 0; q < 8; ++q) sh[n][k + q] = v[q];
    }
    __syncthreads();
    const int lane = tid & 63, wid = tid >> 6;
    const int h0 = (lane & 15) * 4;
    const int nb = wid * 16 + (lane >> 4) * 4;
    float4 a0 = {0,0,0,0}, a1 = {0,0,0,0}, a2 = {0,0,0,0}, a3 = {0,0,0,0};
#pragma unroll 4
    for (int k0 = 0; k0 < 64; k0 += 4) {
        float4 x0 = *reinterpret_cast<float4*>(&sh[nb + 0][k0]);
        float4 x1 = *reinterpret_cast<float4*>(&sh[nb + 1][k0]);
        float4 x2 = *reinterpret_cast<float4*>(&sh[nb + 2][k0]);
        float4 x3 = *reinterpret_cast<float4*>(&sh[nb + 3][k0]);
        float4 w0 = *reinterpret_cast<float4*>(&sw[k0 + 0][h0]);
        float4 w1 = *reinterpret_cast<float4*>(&sw[k0 + 1][h0]);
        float4 w2 = *reinterpret_cast<float4*>(&sw[k0 + 2][h0]);
        float4 w3 = *reinterpret_cast<float4*>(&sw[k0 + 3][h0]);
        FMA4(a0, x0.x, w0); FMA4(a0, x0.y, w1); FMA4(a0, x0.z, w2); FMA4(a0, x0.w, w3);
        FMA4(a1, x1.x, w0); FMA4(a1, x1.y, w1); FMA4(a1, x1.z, w2); FMA4(a1, x1.w, w3);
        FMA4(a2, x2.x, w0); FMA4(a2, x2.y, w1); FMA4(a2, x2.z, w2); FMA4(a2, x2.w, w3);
        FMA4(a3, x3.x, w0); FMA4(a3, x3.y, w1); FMA4(a3, x3.z, w2); FMA4(a3, x3.w, w3);
    }
    if (h0 < 40) {
        int n = n0 + nb;
#pragma unroll
        for (int r = 0; r < 4; ++r) {
            float4 a = (r == 0) ? a0 : (r == 1) ? a1 : (r == 2) ? a2 : a3;
            if (n + r < N) {
                h4 o;
                o.a = __float22half2_rn(make_float2(a.x, a.y));
                o.b = __float22half2_rn(make_float2(a.z, a.w));
                *reinterpret_cast<h4*>(T + (size_t)(n + r) * 40 + h0) = o;
            }
        }
    }
}

// out[n,c] = log_softmax(T[n,:40] + b2), T fp16. One wave per node.
__global__ void k_bias_lsm(const __half* __restrict__ T, const float* __restrict__ b2,
                           float* __restrict__ Y, int N) {
    int gid = blockIdx.x * blockDim.x + threadIdx.x;
    int node = gid >> 6;
    int lane = threadIdx.x & 63;
    if (node >= N) return;
    float v = (lane < 40) ? __half2float(T[(size_t)node * 40 + lane]) + b2[lane] : -INFINITY;
    float m = v;
    for (int off = 32; off >= 1; off >>= 1) m = fmaxf(m, __shfl_xor(m, off));
    float ev = (lane < 40) ? expf(v - m) : 0.0f;
    float s = ev;
    for (int off = 32; off >= 1; off >>= 1) s += __shfl_xor(s, off);
    if (lane < 40) Y[(size_t)node * 40 + lane] = v - m - logf(s);
}

// ---------------- launch ----------------

extern "C" void kernel_launch(void* const* d_in, const int* in_sizes, int n_in,
                              void* d_out, int out_size, void* d_ws, size_t ws_size,
                              hipStream_t stream) {
    const float* x  = (const float*)d_in[0];
    const int*   ei = (const int*)d_in[1];
    const float* W1 = (const float*)d_in[2];
    const float* b1 = (const float*)d_in[3];
    const float* W2 = (const float*)d_in[4];
    const float* b2 = (const float*)d_in[5];
    float* out = (float*)d_out;

    const int H = in_sizes[3];            // 64
    const int F = in_sizes[2] / H;        // 128
    const int N = in_sizes[0] / F;        // 100000
    const int E = in_sizes[1] / 2;        // 1600000
    (void)ws_size; (void)n_in; (void)out_size;

    const int* src = ei;
    const int* dst = ei + E;
    const int NSB = div_up(N, SCH);       // scan blocks (49)

    // workspace layout (4-byte elems for the int/float part)
    const int Npad = (N + 256) & ~255;          // covers N+1
    float* dis  = (float*)d_ws;                 // N
    int*   cnt  = (int*)(dis + Npad);           // N
    int*   rp   = cnt + Npad;                   // N+1
    int*   cur  = rp + Npad;                    // N
    int*   bsum = cur + Npad;                   // NSB
    int*   csrc = bsum + ((NSB + 255) & ~255);  // E
    __half* bufA = (__half*)(csrc + ((E + 255) & ~255));   // N*64 halfs
    __half* bufB = bufA + (size_t)N * 64;                  // N*64 halfs

    const int B = 256;

    // ---- CSR build ----
    k_zero_i32<<<div_up(N, B), B, 0, stream>>>(cnt, N);
    k_cnt<<<div_up(E, B * 4), B, 0, stream>>>(dst, cnt, E);
    k_scan_part<<<NSB, 256, 0, stream>>>(cnt, bsum, N);
    k_scan_bsums<<<1, 1024, 0, stream>>>(bsum, rp + N, NSB);
    k_scan_apply<<<NSB, 256, 0, stream>>>(cnt, bsum, rp, cur, dis, N);
    k_place_direct<<<NXCD * PM, 256, 0, stream>>>(src, dst, cur, csrc, E, N);

    // ---- layer 1 (commuted): Y0 = X @ W1 (fp16), then 2 props at F=64 ----
    k_gemm1<<<div_up(N, 64), 256, 0, stream>>>(x, W1, bufA, N);
    k_prop_h<64><<<div_up((long long)N * 8, B), B, 0, stream>>>(rp, csrc, dis, bufA, bufB, N);
    k_prop_h<64><<<div_up((long long)N * 8, B), B, 0, stream>>>(rp, csrc, dis, bufB, bufA, N);

    // ---- layer 2 (commuted): T = relu(h + b1) @ W2 (fp16), then 2 props at F=40 ----
    k_gemm2<<<div_up(N, 64), 256, 0, stream>>>(bufA, b1, W2, bufB, N);
    k_prop_h<40><<<div_up((long long)N * 5, B), B, 0, stream>>>(rp, csrc, dis, bufB, bufA, N);
    k_prop_h<40><<<div_up((long long)N * 5, B), B, 0, stream>>>(rp, csrc, dis, bufA, bufB, N);

    // ---- epilogue: out = log_softmax(T + b2) ----
    k_bias_lsm<<<div_up((long long)N * 64, 256), 256, 0, stream>>>(bufB, b2, out, N);
}